// Round 12
// baseline (340.210 us; speedup 1.0000x reference)
//
#include <hip/hip_runtime.h>

// ---------------- problem constants ----------------
#define LQ   20197
#define MTOT 40394           // 2 * 20197

typedef _Float16 f16;
typedef _Float16 f16x8 __attribute__((ext_vector_type(8)));
typedef _Float16 f16x4 __attribute__((ext_vector_type(4)));
typedef _Float16 f16x2 __attribute__((ext_vector_type(2)));
typedef float    f32x4 __attribute__((ext_vector_type(4)));

// ---------------- workspace layout (bytes) ----------------
#define OFF_B4 1507328ull      // oa f16 [M,384] -> later y2h f16 [M,256]
#define OFF_B1 42870784ull     // src f16 (residual for LN1)
#define OFF_B2 63552512ull     // query f16 -> later x1h f16
#define OFF_B3 84234240ull     // valueT f16 [8][M][32]
#define OFF_B5 104915968ull    // bias_oa f32 [384]
#define OFF_B6 125597696ull    // src2h f16 [M,256]
#define OFF_B7 166961152ull    // samph f16 [M,256]

// wT element offsets (f16 elements)
#define WT_V    0
#define WT_OFF  65536
#define WT_ATTN 131072
#define WT_OUT  163840
#define WT_W1   229376
#define WT_W2   491520
#define WT_TOTAL 753664
#define WCONV_TOTAL (WT_TOTAL + 384)

// ---------------- async global->LDS, 16B per lane ----------------
__device__ __forceinline__ void gload_lds16(const f16* g, f16* l) {
    __builtin_amdgcn_global_load_lds(
        (const __attribute__((address_space(1))) unsigned int*)g,
        (__attribute__((address_space(3))) unsigned int*)l,
        16, 0, 0);
}

// ---------------- weight transpose+convert + bias concat ----------------
__global__ __launch_bounds__(256) void k_wconv(
    const float* __restrict__ wv, const float* __restrict__ woff,
    const float* __restrict__ wattn, const float* __restrict__ wout,
    const float* __restrict__ w1, const float* __restrict__ w2,
    const float* __restrict__ boff, const float* __restrict__ battn,
    f16* __restrict__ dst, float* __restrict__ biasoa)
{
    int gid = blockIdx.x * 256 + threadIdx.x;
    if (gid >= WCONV_TOTAL) return;
    if (gid >= WT_TOTAL) {
        int i = gid - WT_TOTAL;
        biasoa[i] = (i < 256) ? boff[i] : battn[i - 256];
        return;
    }
    const float* src; int Kd, Nd, base;
    if      (gid < 65536)  { src = wv;    Kd = 256;  Nd = 256;  base = 0; }
    else if (gid < 131072) { src = woff;  Kd = 256;  Nd = 256;  base = 65536; }
    else if (gid < 163840) { src = wattn; Kd = 256;  Nd = 128;  base = 131072; }
    else if (gid < 229376) { src = wout;  Kd = 256;  Nd = 256;  base = 163840; }
    else if (gid < 491520) { src = w1;    Kd = 256;  Nd = 1024; base = 229376; }
    else                   { src = w2;    Kd = 1024; Nd = 256;  base = 491520; }
    int loc = gid - base;
    int n = loc % Nd, k = loc / Nd;
    dst[base + n * Kd + k] = (f16)src[k * Nd + n];
}

// ---------------- prep: query = src + pos, cast both to f16 ----------------
__global__ __launch_bounds__(256) void k_prep(
    const float* __restrict__ src, const float* __restrict__ pos,
    f16* __restrict__ srch, f16* __restrict__ qh, int total4)
{
    int i = blockIdx.x * 256 + threadIdx.x;
    if (i >= total4) return;
    float4 s = ((const float4*)src)[i];
    float4 p = ((const float4*)pos)[i];
    f16x4 hs = { (f16)s.x, (f16)s.y, (f16)s.z, (f16)s.w };
    f16x4 hq = { (f16)(s.x + p.x), (f16)(s.y + p.y), (f16)(s.z + p.z), (f16)(s.w + p.w) };
    ((f16x4*)srch)[i] = hs;
    ((f16x4*)qh)[i]   = hq;
}

// ---------------- GEMM 128x128 tile, BK=32, dbuf global_load_lds, XCD swizzle ----------------
// OUTM: 1 = f16 row-major [M][N], 2 = f16 head-blocked [N/32][M][32]
template<bool RELU, int OUTM>
__global__ __launch_bounds__(256) void k_gemm128(
    const f16* __restrict__ A, const f16* __restrict__ Bt,
    const float* __restrict__ bias, void* __restrict__ Cout,
    int M, int N, int K)
{
    __shared__ __align__(16) char pool[34816];
    f16* const sm = (f16*)pool;

    const int NBn = N >> 7;
    const int MBn = (M + 127) >> 7;
    const int tiles = MBn * NBn;
    const int q = gridDim.x >> 3;
    const int bid = blockIdx.x;
    const int swz = (bid & 7) * q + (bid >> 3);
    if (swz >= tiles) return;
    const int m0 = (swz / NBn) << 7;
    const int n0 = (swz % NBn) << 7;

    const int t = threadIdx.x, wid = t >> 6, lane = t & 63;

    const int c0 = wid, c1 = wid + 4;
    const int sr = lane >> 2, sk = (lane & 3) * 8;
    const int ra0 = min(m0 + c0 * 16 + sr, M - 1);
    const int ra1 = min(m0 + c1 * 16 + sr, M - 1);
    const f16* pa0 = A + (size_t)ra0 * K + sk;
    const f16* pa1 = A + (size_t)ra1 * K + sk;
    const f16* pb0 = Bt + (size_t)(n0 + c0 * 16 + sr) * K + sk;
    const f16* pb1 = Bt + (size_t)(n0 + c1 * 16 + sr) * K + sk;
    const int lo0 = c0 * 512, lo1 = c1 * 512;

    const int wr = wid >> 1, wc = wid & 1;
    const int fr = lane & 15, kb = (lane >> 4) * 8;

    f32x4 acc[4][4] = {};
    const int NT = K >> 5;

    gload_lds16(pa0, sm + lo0);
    gload_lds16(pa1, sm + lo1);
    gload_lds16(pb0, sm + 4096 + lo0);
    gload_lds16(pb1, sm + 4096 + lo1);
    __syncthreads();

    for (int tt = 0; tt < NT; ++tt) {
        const int cur = (tt & 1) << 13, nxt = cur ^ 8192;
        if (tt + 1 < NT) {
            const int k0 = (tt + 1) << 5;
            gload_lds16(pa0 + k0, sm + nxt + lo0);
            gload_lds16(pa1 + k0, sm + nxt + lo1);
            gload_lds16(pb0 + k0, sm + nxt + 4096 + lo0);
            gload_lds16(pb1 + k0, sm + nxt + 4096 + lo1);
        }
        f16x8 af[4], bf[4];
#pragma unroll
        for (int i = 0; i < 4; ++i)
            af[i] = *(const f16x8*)&sm[cur + (wr * 64 + i * 16 + fr) * 32 + kb];
#pragma unroll
        for (int i = 0; i < 4; ++i)
            bf[i] = *(const f16x8*)&sm[cur + 4096 + (wc * 64 + i * 16 + fr) * 32 + kb];
#pragma unroll
        for (int mi = 0; mi < 4; ++mi)
#pragma unroll
            for (int ni = 0; ni < 4; ++ni)
                acc[mi][ni] = __builtin_amdgcn_mfma_f32_16x16x32_f16(af[mi], bf[ni], acc[mi][ni], 0, 0, 0);
        __syncthreads();
    }

    const int r4 = (lane >> 4) * 4;
#pragma unroll
    for (int ni = 0; ni < 4; ++ni) {
        const int lcol = wc * 64 + ni * 16 + fr;
        const float bv = bias[n0 + lcol];
#pragma unroll
        for (int mi = 0; mi < 4; ++mi) {
#pragma unroll
            for (int j = 0; j < 4; ++j) {
                float v = acc[mi][ni][j] + bv;
                if (RELU) v = fmaxf(v, 0.f);
                sm[(wr * 64 + mi * 16 + r4 + j) * 136 + lcol] = (f16)v;
            }
        }
    }
    __syncthreads();

    if (OUTM == 1) {
        const int rr = t >> 4, cc = (t & 15) * 8;
#pragma unroll
        for (int pass = 0; pass < 8; ++pass) {
            const int r = pass * 16 + rr;
            const int row = m0 + r;
            if (row < M) {
                f16x8 v = *(const f16x8*)&sm[r * 136 + cc];
                *(f16x8*)&((f16*)Cout)[(size_t)row * N + n0 + cc] = v;
            }
        }
    } else {
        const int cbl = t >> 6, rr = (t & 63) >> 2, cc = (t & 3) * 8;
        const size_t cb = (size_t)((n0 >> 5) + cbl);
#pragma unroll
        for (int pass = 0; pass < 8; ++pass) {
            const int r = pass * 16 + rr;
            const int row = m0 + r;
            if (row < M) {
                f16x8 v = *(const f16x8*)&sm[r * 136 + cbl * 32 + cc];
                *(f16x8*)&((f16*)Cout)[(cb * M + row) * 32 + cc] = v;
            }
        }
    }
}

// ---------------- fused FFN: y2 = relu(x1@W1t^T + b1) @ W2t^T + b2 ----------------
// BM=32 rows/block, 4 waves. x1-tile (16KB) and h-tile (64KB, k-chunked [32][32]
// with XOR-granule swizzle) live in LDS; W1/W2 B-fragments read directly from
// global (1MB total, L2-resident). Kills the 165MB hh HBM round-trip.
__global__ __launch_bounds__(256) void k_ffn(
    const f16* __restrict__ x1, const f16* __restrict__ w1t,
    const float* __restrict__ b1, const f16* __restrict__ w2t,
    const float* __restrict__ b2, f16* __restrict__ y2, int M)
{
    __shared__ __align__(16) char pool[81920];   // A 16KB | h 64KB ; epi aliases front
    f16* const A_lds = (f16*)pool;               // 8 chunks x [32][32]
    f16* const h_lds = (f16*)pool + 8192;        // 32 chunks x [32][32], swizzled
    f16* const epi   = (f16*)pool;               // [32][264] after GEMM2

    const int nblk = (M + 31) >> 5;
    const int q = gridDim.x >> 3;
    const int swz = ((int)blockIdx.x & 7) * q + ((int)blockIdx.x >> 3);
    if (swz >= nblk) return;
    const int m0 = swz << 5;

    const int t = threadIdx.x, w = t >> 6, lane = t & 63;
    const int fr = lane & 15, qd = lane >> 4;   // fragment row / k-quarter
    const int kb = qd * 8, r4 = qd * 4;

    // ---- stage x1 tile [32 rows][256] as 8 k-chunks of [32][32] ----
#pragma unroll
    for (int i = 0; i < 4; ++i) {
        const int id = w * 4 + i, c = id >> 1, half = id & 1;
        const int row = min(m0 + half * 16 + (lane >> 2), M - 1);
        gload_lds16(x1 + (size_t)row * 256 + c * 32 + (lane & 3) * 8,
                    A_lds + c * 1024 + half * 512);
    }
    __syncthreads();

    // ---- GEMM1: h[32][1024] = relu(x1 @ W1t^T + b1), wave w -> cols w*32 per nchunk ----
    for (int nc = 0; nc < 8; ++nc) {
        f32x4 acc1[2][2] = {};
        const int nbase = nc * 128 + w * 32;
#pragma unroll 2
        for (int kc = 0; kc < 8; ++kc) {
            f16x8 af[2], bf[2];
#pragma unroll
            for (int mi = 0; mi < 2; ++mi)
                af[mi] = *(const f16x8*)&A_lds[kc * 1024 + (mi * 16 + fr) * 32 + kb];
#pragma unroll
            for (int ni = 0; ni < 2; ++ni)
                bf[ni] = *(const f16x8*)&w1t[(size_t)(nbase + ni * 16 + fr) * 256 + kc * 32 + kb];
#pragma unroll
            for (int mi = 0; mi < 2; ++mi)
#pragma unroll
                for (int ni = 0; ni < 2; ++ni)
                    acc1[mi][ni] = __builtin_amdgcn_mfma_f32_16x16x32_f16(af[mi], bf[ni], acc1[mi][ni], 0, 0, 0);
        }
        const int hc = nc * 4 + w;      // h k-chunk this wave owns
#pragma unroll
        for (int ni = 0; ni < 2; ++ni) {
            const float bv = b1[nbase + ni * 16 + fr];
            const int col = ni * 16 + fr;          // 0..31 within chunk
#pragma unroll
            for (int mi = 0; mi < 2; ++mi)
#pragma unroll
                for (int j = 0; j < 4; ++j) {
                    const int row = mi * 16 + r4 + j;
                    const float v = fmaxf(acc1[mi][ni][j] + bv, 0.f);
                    const int g = (col >> 3) ^ ((row >> 2) & 3);   // XOR-granule swizzle
                    h_lds[hc * 1024 + row * 32 + g * 8 + (col & 7)] = (f16)v;
                }
        }
    }
    __syncthreads();

    // ---- GEMM2: y2[32][256] = h @ W2t^T + b2 ; wave w -> cols w*64 ----
    f32x4 acc2[2][4] = {};
    const int swzg = (qd ^ ((fr >> 2) & 3)) << 3;   // swizzled granule offset for reads
#pragma unroll 2
    for (int kc = 0; kc < 32; ++kc) {
        f16x8 af[2], bf[4];
#pragma unroll
        for (int mi = 0; mi < 2; ++mi)
            af[mi] = *(const f16x8*)&h_lds[kc * 1024 + (mi * 16 + fr) * 32 + swzg];
#pragma unroll
        for (int ni = 0; ni < 4; ++ni)
            bf[ni] = *(const f16x8*)&w2t[(size_t)(w * 64 + ni * 16 + fr) * 1024 + kc * 32 + kb];
#pragma unroll
        for (int mi = 0; mi < 2; ++mi)
#pragma unroll
            for (int ni = 0; ni < 4; ++ni)
                acc2[mi][ni] = __builtin_amdgcn_mfma_f32_16x16x32_f16(af[mi], bf[ni], acc2[mi][ni], 0, 0, 0);
    }
    __syncthreads();   // h & A dead; epi aliases pool front

    // ---- epilogue: stage [32][264] then coalesced write ----
#pragma unroll
    for (int ni = 0; ni < 4; ++ni) {
        const int col = w * 64 + ni * 16 + fr;
        const float bv = b2[col];
#pragma unroll
        for (int mi = 0; mi < 2; ++mi)
#pragma unroll
            for (int j = 0; j < 4; ++j)
                epi[(mi * 16 + r4 + j) * 264 + col] = (f16)(acc2[mi][ni][j] + bv);
    }
    __syncthreads();
    {
        const int row = t >> 3, cb = (t & 7) * 32;
        if (m0 + row < M) {
#pragma unroll
            for (int i = 0; i < 4; ++i)
                *(f16x8*)&y2[(size_t)(m0 + row) * 256 + cb + i * 8] =
                    *(const f16x8*)&epi[row * 264 + cb + i * 8];
        }
    }
}

// ---------------- fused softmax + deformable bilinear sampling ----------------
// Head-split (head = blockIdx.x & 7 -> XCD L2 slab) + point-split; at the L2
// request-rate floor (~65us, 20.7M 64B line requests).
__global__ __launch_bounds__(256) void k_sample(
    const f16* __restrict__ oa, const f16* __restrict__ valueT,
    const float* __restrict__ ref, f16* __restrict__ samp)
{
    __shared__ uint2 s_g[32][17];
    __shared__ f16x4 s_w[32][17];
    const int head = blockIdx.x & 7;
    const int tok0 = (blockIdx.x >> 3) * 32;
    const int t = threadIdx.x;

#pragma unroll
    for (int it = 0; it < 2; ++it) {
        const int tl = it * 16 + (t >> 4);
        const int lp = t & 15, l = lp >> 2;
        const int tok = tok0 + tl;
        if (tok < MTOT) {
            const size_t row = (size_t)tok * 384;
            float logit = (float)oa[row + 256 + head * 16 + lp];
            float mx = logit;
#pragma unroll
            for (int m = 1; m < 16; m <<= 1) mx = fmaxf(mx, __shfl_xor(mx, m));
            float e = __expf(logit - mx);
            float sum = e;
#pragma unroll
            for (int m = 1; m < 16; m <<= 1) sum += __shfl_xor(sum, m);
            const float aw = e / sum;

            const float fW = (l == 0) ? 152.f : (l == 1) ? 76.f : (l == 2) ? 38.f : 19.f;
            const float fH = (l == 0) ? 100.f : (l == 1) ? 50.f : (l == 2) ? 25.f : 13.f;
            const int   W  = (l == 0) ? 152 : (l == 1) ? 76 : (l == 2) ? 38 : 19;
            const int   H  = (l == 0) ? 100 : (l == 1) ? 50 : (l == 2) ? 25 : 13;
            const int   st = (l == 0) ? 0 : (l == 1) ? 15200 : (l == 2) ? 19000 : 19950;

            const f16x2 ov = *(const f16x2*)&oa[row + head * 32 + lp * 2];
            const float2 rxy = *(const float2*)&ref[(size_t)tok * 8 + l * 2];
            const float x = rxy.x * fW + (float)ov.x - 0.5f;
            const float y = rxy.y * fH + (float)ov.y - 0.5f;
            const float xf = floorf(x), yf = floorf(y);
            const float fx = x - xf, fy = y - yf;
            const int x0 = (int)xf, y0 = (int)yf;

            const bool vx0 = (x0 >= 0) && (x0 < W);
            const bool vx1 = (x0 >= -1) && (x0 < W - 1);
            const bool vy0 = (y0 >= 0) && (y0 < H);
            const bool vy1 = (y0 >= -1) && (y0 < H - 1);
            const int x0c = min(max(x0, 0), W - 1), x1c = min(max(x0 + 1, 0), W - 1);
            const int y0c = min(max(y0, 0), H - 1), y1c = min(max(y0 + 1, 0), H - 1);

            const int n = (tok >= LQ) ? 1 : 0;
            const unsigned int b00 = (unsigned int)(n * LQ + st + y0c * W + x0c) << 6;
            const unsigned int dx6 = (unsigned int)(x1c - x0c) << 6;
            const unsigned int dy6 = (unsigned int)((y1c - y0c) * W) << 6;
            s_g[tl][lp] = make_uint2(b00, dx6 | (dy6 << 16));

            const f16 w00 = (f16)((vx0 && vy0) ? (1.f - fx) * (1.f - fy) * aw : 0.f);
            const f16 w01 = (f16)((vx1 && vy0) ? fx * (1.f - fy) * aw : 0.f);
            const f16 w10 = (f16)((vx0 && vy1) ? (1.f - fx) * fy * aw : 0.f);
            const f16 w11 = (f16)((vx1 && vy1) ? fx * fy * aw : 0.f);
            f16x4 wv = { w00, w01, w10, w11 };
            s_w[tl][lp] = wv;
        }
    }
    __syncthreads();

    const int tl = t >> 3;
    const int sub = (t >> 2) & 1;
    const int l4 = t & 3;
    const int tok = tok0 + tl;
    if (tok >= MTOT) return;
    const unsigned int lb = (unsigned int)l4 * 16u;
    const char* vbase = (const char*)valueT + (size_t)head * (MTOT * 64ull);
    const int pbase = sub * 8;

    f16x2 a0 = {}, a1 = {}, a2 = {}, a3 = {};
#pragma unroll
    for (int pi = 0; pi < 8; ++pi) {
        const int p = pbase + pi;
        const uint2 g  = s_g[tl][p];
        const f16x4 wv = s_w[tl][p];
        const unsigned int a00 = g.x + lb;
        const unsigned int dx6 = g.y & 0xFFFFu;
        const unsigned int dy6 = g.y >> 16;
        const f16x8 v00 = *(const f16x8*)(vbase + a00);
        const f16x8 v01 = *(const f16x8*)(vbase + (a00 + dx6));
        const f16x8 v10 = *(const f16x8*)(vbase + (a00 + dy6));
        const f16x8 v11 = *(const f16x8*)(vbase + (a00 + dy6 + dx6));
        const f16x2 w0 = { wv[0], wv[0] }, w1 = { wv[1], wv[1] };
        const f16x2 w2 = { wv[2], wv[2] }, w3 = { wv[3], wv[3] };
        const f16x2* p0 = (const f16x2*)&v00;
        const f16x2* p1 = (const f16x2*)&v01;
        const f16x2* p2 = (const f16x2*)&v10;
        const f16x2* p3 = (const f16x2*)&v11;
        a0 = a0 + p0[0] * w0; a1 = a1 + p0[1] * w0;
        a2 = a2 + p0[2] * w0; a3 = a3 + p0[3] * w0;
        a0 = a0 + p1[0] * w1; a1 = a1 + p1[1] * w1;
        a2 = a2 + p1[2] * w1; a3 = a3 + p1[3] * w1;
        a0 = a0 + p2[0] * w2; a1 = a1 + p2[1] * w2;
        a2 = a2 + p2[2] * w2; a3 = a3 + p2[3] * w2;
        a0 = a0 + p3[0] * w3; a1 = a1 + p3[1] * w3;
        a2 = a2 + p3[2] * w3; a3 = a3 + p3[3] * w3;
    }

    union { f16x2 h; int i; } u0, u1, u2, u3;
    u0.h = a0; u1.h = a1; u2.h = a2; u3.h = a3;
    union { int i; f16x2 h; } r0, r1, r2, r3;
    r0.i = __shfl_xor(u0.i, 4); r1.i = __shfl_xor(u1.i, 4);
    r2.i = __shfl_xor(u2.i, 4); r3.i = __shfl_xor(u3.i, 4);
    a0 = a0 + r0.h; a1 = a1 + r1.h; a2 = a2 + r2.h; a3 = a3 + r3.h;

    f16x4 o = sub ? (f16x4){ a2.x, a2.y, a3.x, a3.y }
                  : (f16x4){ a0.x, a0.y, a1.x, a1.y };
    *(f16x4*)&samp[(size_t)tok * 256 + head * 32 + l4 * 8 + sub * 4] = o;
}

// ---------------- LN (f16 inputs): y = LN(xa + xb)*g + b ----------------
template<int OUTF16>
__global__ __launch_bounds__(256) void k_lnh(
    const f16* __restrict__ xa, const f16* __restrict__ xb,
    const float* __restrict__ g, const float* __restrict__ be,
    void* __restrict__ y, int M)
{
    const int row = blockIdx.x * 4 + (threadIdx.x >> 6);
    const int lane = threadIdx.x & 63;
    if (row >= M) return;
    const size_t o = (size_t)row * 256 + lane * 4;
    f16x4 a = *(const f16x4*)(xa + o);
    f16x4 b = *(const f16x4*)(xb + o);
    float x0 = (float)a.x + (float)b.x, x1 = (float)a.y + (float)b.y;
    float x2 = (float)a.z + (float)b.z, x3 = (float)a.w + (float)b.w;
    float s  = x0 + x1 + x2 + x3;
    float ss = x0*x0 + x1*x1 + x2*x2 + x3*x3;
#pragma unroll
    for (int m = 1; m < 64; m <<= 1) { s += __shfl_xor(s, m); ss += __shfl_xor(ss, m); }
    const float mean = s * (1.f / 256.f);
    const float var  = ss * (1.f / 256.f) - mean * mean;
    const float rstd = rsqrtf(var + 1e-5f);
    float4 gv = *(const float4*)(g + lane * 4);
    float4 bv = *(const float4*)(be + lane * 4);
    const float y0 = (x0 - mean) * rstd * gv.x + bv.x;
    const float y1 = (x1 - mean) * rstd * gv.y + bv.y;
    const float y2 = (x2 - mean) * rstd * gv.z + bv.z;
    const float y3 = (x3 - mean) * rstd * gv.w + bv.w;
    if (OUTF16) {
        f16x4 hv = { (f16)y0, (f16)y1, (f16)y2, (f16)y3 };
        *(f16x4*)((f16*)y + o) = hv;
    } else {
        float4 yo = { y0, y1, y2, y3 };
        *(float4*)((float*)y + o) = yo;
    }
}

// ---------------- launch ----------------
extern "C" void kernel_launch(void* const* d_in, const int* in_sizes, int n_in,
                              void* d_out, int out_size, void* d_ws, size_t ws_size,
                              hipStream_t stream) {
    const float* src   = (const float*)d_in[0];
    const float* pos   = (const float*)d_in[1];
    const float* ref   = (const float*)d_in[2];
    const float* w_value = (const float*)d_in[5];
    const float* b_value = (const float*)d_in[6];
    const float* w_off   = (const float*)d_in[7];
    const float* b_off   = (const float*)d_in[8];
    const float* w_attn  = (const float*)d_in[9];
    const float* b_attn  = (const float*)d_in[10];
    const float* w_out   = (const float*)d_in[11];
    const float* b_out   = (const float*)d_in[12];
    const float* g1    = (const float*)d_in[13];
    const float* beta1 = (const float*)d_in[14];
    const float* w1    = (const float*)d_in[15];
    const float* b1    = (const float*)d_in[16];
    const float* w2    = (const float*)d_in[17];
    const float* b2    = (const float*)d_in[18];
    const float* g2    = (const float*)d_in[19];
    const float* beta2 = (const float*)d_in[20];

    char* ws = (char*)d_ws;
    f16*   wT      = (f16*)(ws + 0);
    f16*   oa      = (f16*)(ws + OFF_B4);     // fused off|attn f16 [M,384]
    f16*   y2h     = (f16*)(ws + OFF_B4);     // later: FFN out f16 [M,256] (oa dead)
    f16*   srch    = (f16*)(ws + OFF_B1);     // src f16 (residual for LN1)
    f16*   qh      = (f16*)(ws + OFF_B2);     // query f16
    f16*   x1h     = (f16*)(ws + OFF_B2);     // later: LN1 out f16
    f16*   valueT  = (f16*)(ws + OFF_B3);     // value f16 head-blocked [8][M][32]
    float* biasoa  = (float*)(ws + OFF_B5);   // concat bias f32 [384]
    f16*   src2h   = (f16*)(ws + OFF_B6);     // attn output f16 [M,256]
    f16*   samph   = (f16*)(ws + OFF_B7);     // sampled out f16 [M,256]
    float* outp    = (float*)d_out;

    const int M = MTOT;
    const int MB = (M + 127) / 128;
    auto grid8 = [&](int nb) { return ((MB * nb) + 7) & ~7; };

    k_wconv<<<(WCONV_TOTAL + 255) / 256, 256, 0, stream>>>(
        w_value, w_off, w_attn, w_out, w1, w2, b_off, b_attn, wT, biasoa);
    k_prep<<<(M * 64 + 255) / 256, 256, 0, stream>>>(src, pos, srch, qh, M * 64);

    // value = src @ w_value + b_value -> head-blocked f16
    k_gemm128<false, 2><<<grid8(2), 256, 0, stream>>>(srch, wT + WT_V, b_value, valueT, M, 256, 256);
    // fused off|attn logits -> f16 [M,384]
    k_gemm128<false, 1><<<grid8(3), 256, 0, stream>>>(qh, wT + WT_OFF, biasoa, oa, M, 384, 256);
    // softmax + bilinear sampling
    {
        const int nchunk = (MTOT + 31) / 32;
        k_sample<<<dim3(nchunk * 8), 256, 0, stream>>>(oa, valueT, ref, samph);
    }
    // out projection -> src2 f16
    k_gemm128<false, 1><<<grid8(2), 256, 0, stream>>>(samph, wT + WT_OUT, b_out, src2h, M, 256, 256);
    // LN1: x1h = LN(srch + src2h) f16
    k_lnh<1><<<(M + 3) / 4, 256, 0, stream>>>(srch, src2h, g1, beta1, x1h, M);
    // fused FFN: y2h = relu(x1h@W1+b1)@W2 + b2  (hh round-trip eliminated)
    {
        const int nblk = (M + 31) / 32;
        const int g = (nblk + 7) & ~7;
        k_ffn<<<dim3(g), 256, 0, stream>>>(x1h, wT + WT_W1, b1, wT + WT_W2, b2, y2h, M);
    }
    // LN2 -> d_out f32
    k_lnh<0><<<(M + 3) / 4, 256, 0, stream>>>(x1h, y2h, g2, beta2, outp, M);

    (void)in_sizes; (void)n_in; (void)out_size; (void)ws_size;
}

// Round 13
// 220.445 us; speedup vs baseline: 1.5433x; 1.5433x over previous
//
#include <hip/hip_runtime.h>

// ---------------- problem constants ----------------
#define LQ   20197
#define MTOT 40394           // 2 * 20197

typedef _Float16 f16;
typedef _Float16 f16x8 __attribute__((ext_vector_type(8)));
typedef _Float16 f16x4 __attribute__((ext_vector_type(4)));
typedef _Float16 f16x2 __attribute__((ext_vector_type(2)));
typedef float    f32x4 __attribute__((ext_vector_type(4)));

// ---------------- workspace layout (bytes) ----------------
#define OFF_B4 1507328ull      // oa f16 [M,384] -> later y2h f16 [M,256]
#define OFF_B1 42870784ull     // src f16 (residual for LN1)
#define OFF_B2 63552512ull     // query f16 -> later x1h f16
#define OFF_B3 84234240ull     // valueT f16 [8][M][32]; later FFN hidden hh (B3..B7)
#define OFF_B5 104915968ull    // bias_oa f32 [384] (consumed before FFN1)
#define OFF_B6 125597696ull    // src2h f16 [M,256] (consumed before FFN1)
#define OFF_B7 166961152ull    // samph f16 [M,256] (consumed by out-proj GEMM)

// wT element offsets (f16 elements)
#define WT_V    0
#define WT_OFF  65536          // off rows [256][256] then attn rows [128][256] contiguous
#define WT_ATTN 131072
#define WT_OUT  163840
#define WT_W1   229376
#define WT_W2   491520
#define WT_TOTAL 753664
#define WCONV_TOTAL (WT_TOTAL + 384)
#define PREP_TOTAL (MTOT * 64)          // float4 groups
#define FUSED_TOTAL (WCONV_TOTAL + PREP_TOTAL)

// ---------------- async global->LDS, 16B per lane ----------------
__device__ __forceinline__ void gload_lds16(const f16* g, f16* l) {
    __builtin_amdgcn_global_load_lds(
        (const __attribute__((address_space(1))) unsigned int*)g,
        (__attribute__((address_space(3))) unsigned int*)l,
        16, 0, 0);
}

// ---------------- fused: weight transpose+convert + bias concat + prep ----------------
__global__ __launch_bounds__(256) void k_wconv_prep(
    const float* __restrict__ wv, const float* __restrict__ woff,
    const float* __restrict__ wattn, const float* __restrict__ wout,
    const float* __restrict__ w1, const float* __restrict__ w2,
    const float* __restrict__ boff, const float* __restrict__ battn,
    f16* __restrict__ dst, float* __restrict__ biasoa,
    const float* __restrict__ srcf, const float* __restrict__ posf,
    f16* __restrict__ srch, f16* __restrict__ qh)
{
    int gid = blockIdx.x * 256 + threadIdx.x;
    if (gid >= FUSED_TOTAL) return;
    if (gid >= WCONV_TOTAL) {
        // prep: query = src + pos, cast both to f16 (float4 granularity)
        const int i = gid - WCONV_TOTAL;
        float4 s = ((const float4*)srcf)[i];
        float4 p = ((const float4*)posf)[i];
        f16x4 hs = { (f16)s.x, (f16)s.y, (f16)s.z, (f16)s.w };
        f16x4 hq = { (f16)(s.x + p.x), (f16)(s.y + p.y), (f16)(s.z + p.z), (f16)(s.w + p.w) };
        ((f16x4*)srch)[i] = hs;
        ((f16x4*)qh)[i]   = hq;
        return;
    }
    if (gid >= WT_TOTAL) {
        int i = gid - WT_TOTAL;
        biasoa[i] = (i < 256) ? boff[i] : battn[i - 256];
        return;
    }
    const float* src; int Kd, Nd, base;
    if      (gid < 65536)  { src = wv;    Kd = 256;  Nd = 256;  base = 0; }
    else if (gid < 131072) { src = woff;  Kd = 256;  Nd = 256;  base = 65536; }
    else if (gid < 163840) { src = wattn; Kd = 256;  Nd = 128;  base = 131072; }
    else if (gid < 229376) { src = wout;  Kd = 256;  Nd = 256;  base = 163840; }
    else if (gid < 491520) { src = w1;    Kd = 256;  Nd = 1024; base = 229376; }
    else                   { src = w2;    Kd = 1024; Nd = 256;  base = 491520; }
    int loc = gid - base;
    int n = loc % Nd, k = loc / Nd;
    dst[base + n * Kd + k] = (f16)src[k * Nd + n];
}

// ---------------- GEMM 128x128 tile, BK=32, dbuf global_load_lds, XCD swizzle ----------------
// C[M,N] = A[M,K](f16) * Bt[N,K](f16)^T + bias ; N % 128 == 0 assumed.
// OUTM: 1 = f16 row-major [M][N], 2 = f16 head-blocked [N/32][M][32]
template<bool RELU, int OUTM>
__global__ __launch_bounds__(256) void k_gemm128(
    const f16* __restrict__ A, const f16* __restrict__ Bt,
    const float* __restrict__ bias, void* __restrict__ Cout,
    int M, int N, int K)
{
    __shared__ __align__(16) char pool[34816];   // staging 32KB  |  C-tile 128*136*2B
    f16* const sm = (f16*)pool;

    const int NBn = N >> 7;
    const int MBn = (M + 127) >> 7;
    const int tiles = MBn * NBn;
    const int q = gridDim.x >> 3;                 // grid padded to %8
    const int bid = blockIdx.x;
    const int swz = (bid & 7) * q + (bid >> 3);   // bijective XCD swizzle
    if (swz >= tiles) return;
    const int m0 = (swz / NBn) << 7;
    const int n0 = (swz % NBn) << 7;

    const int t = threadIdx.x, wid = t >> 6, lane = t & 63;

    const int c0 = wid, c1 = wid + 4;
    const int sr = lane >> 2, sk = (lane & 3) * 8;
    const int ra0 = min(m0 + c0 * 16 + sr, M - 1);
    const int ra1 = min(m0 + c1 * 16 + sr, M - 1);
    const f16* pa0 = A + (size_t)ra0 * K + sk;
    const f16* pa1 = A + (size_t)ra1 * K + sk;
    const f16* pb0 = Bt + (size_t)(n0 + c0 * 16 + sr) * K + sk;
    const f16* pb1 = Bt + (size_t)(n0 + c1 * 16 + sr) * K + sk;
    const int lo0 = c0 * 512, lo1 = c1 * 512;

    const int wr = wid >> 1, wc = wid & 1;
    const int fr = lane & 15, kb = (lane >> 4) * 8;

    f32x4 acc[4][4] = {};
    const int NT = K >> 5;

    gload_lds16(pa0, sm + lo0);
    gload_lds16(pa1, sm + lo1);
    gload_lds16(pb0, sm + 4096 + lo0);
    gload_lds16(pb1, sm + 4096 + lo1);
    __syncthreads();

    for (int tt = 0; tt < NT; ++tt) {
        const int cur = (tt & 1) << 13, nxt = cur ^ 8192;
        if (tt + 1 < NT) {
            const int k0 = (tt + 1) << 5;
            gload_lds16(pa0 + k0, sm + nxt + lo0);
            gload_lds16(pa1 + k0, sm + nxt + lo1);
            gload_lds16(pb0 + k0, sm + nxt + 4096 + lo0);
            gload_lds16(pb1 + k0, sm + nxt + 4096 + lo1);
        }
        f16x8 af[4], bf[4];
#pragma unroll
        for (int i = 0; i < 4; ++i)
            af[i] = *(const f16x8*)&sm[cur + (wr * 64 + i * 16 + fr) * 32 + kb];
#pragma unroll
        for (int i = 0; i < 4; ++i)
            bf[i] = *(const f16x8*)&sm[cur + 4096 + (wc * 64 + i * 16 + fr) * 32 + kb];
#pragma unroll
        for (int mi = 0; mi < 4; ++mi)
#pragma unroll
            for (int ni = 0; ni < 4; ++ni)
                acc[mi][ni] = __builtin_amdgcn_mfma_f32_16x16x32_f16(af[mi], bf[ni], acc[mi][ni], 0, 0, 0);
        __syncthreads();
    }

    // ---- epilogue: acc -> LDS (stride 136) -> coalesced global ----
    const int r4 = (lane >> 4) * 4;
#pragma unroll
    for (int ni = 0; ni < 4; ++ni) {
        const int lcol = wc * 64 + ni * 16 + fr;
        const float bv = bias[n0 + lcol];
#pragma unroll
        for (int mi = 0; mi < 4; ++mi) {
#pragma unroll
            for (int j = 0; j < 4; ++j) {
                float v = acc[mi][ni][j] + bv;
                if (RELU) v = fmaxf(v, 0.f);
                sm[(wr * 64 + mi * 16 + r4 + j) * 136 + lcol] = (f16)v;
            }
        }
    }
    __syncthreads();

    if (OUTM == 1) {
        const int rr = t >> 4, cc = (t & 15) * 8;
#pragma unroll
        for (int pass = 0; pass < 8; ++pass) {
            const int r = pass * 16 + rr;
            const int row = m0 + r;
            if (row < M) {
                f16x8 v = *(const f16x8*)&sm[r * 136 + cc];
                *(f16x8*)&((f16*)Cout)[(size_t)row * N + n0 + cc] = v;
            }
        }
    } else {
        const int cbl = t >> 6, rr = (t & 63) >> 2, cc = (t & 3) * 8;
        const size_t cb = (size_t)((n0 >> 5) + cbl);
#pragma unroll
        for (int pass = 0; pass < 8; ++pass) {
            const int r = pass * 16 + rr;
            const int row = m0 + r;
            if (row < M) {
                f16x8 v = *(const f16x8*)&sm[r * 136 + cbl * 32 + cc];
                *(f16x8*)&((f16*)Cout)[(cb * M + row) * 32 + cc] = v;
            }
        }
    }
}

// ---------------- fused softmax + deformable bilinear sampling ----------------
// HEAD-SPLIT for L2 locality: block = (head, 64 tokens); head = blockIdx.x & 7
// -> round-robin dispatch pins head h to XCD h; one head's value slab
// ([M][32] f16 = 2.59 MB) fits in the XCD's 4 MB L2 -> gathers are L2 hits.
// At the L2 request-rate floor (~65us, 20.7M 64B line requests / dispatch).
__global__ __launch_bounds__(256) void k_sample(
    const f16* __restrict__ oa, const f16* __restrict__ valueT,
    const float* __restrict__ ref, f16* __restrict__ samp)
{
    __shared__ uint2 s_g[64][17];   // (b00 bytes, dx6 | dy6<<16); pad 17 for banks
    __shared__ f16x4 s_w[64][17];   // (w00,w01,w10,w11) premultiplied by attn
    const int head = blockIdx.x & 7;
    const int tok0 = (blockIdx.x >> 3) * 64;
    const int t = threadIdx.x;

#pragma unroll
    for (int it = 0; it < 4; ++it) {
        const int tl = it * 16 + (t >> 4);
        const int lp = t & 15, l = lp >> 2;
        const int tok = tok0 + tl;
        if (tok < MTOT) {
            const size_t row = (size_t)tok * 384;
            float logit = (float)oa[row + 256 + head * 16 + lp];
            float mx = logit;
#pragma unroll
            for (int m = 1; m < 16; m <<= 1) mx = fmaxf(mx, __shfl_xor(mx, m));
            float e = __expf(logit - mx);
            float sum = e;
#pragma unroll
            for (int m = 1; m < 16; m <<= 1) sum += __shfl_xor(sum, m);
            const float aw = e / sum;

            const float fW = (l == 0) ? 152.f : (l == 1) ? 76.f : (l == 2) ? 38.f : 19.f;
            const float fH = (l == 0) ? 100.f : (l == 1) ? 50.f : (l == 2) ? 25.f : 13.f;
            const int   W  = (l == 0) ? 152 : (l == 1) ? 76 : (l == 2) ? 38 : 19;
            const int   H  = (l == 0) ? 100 : (l == 1) ? 50 : (l == 2) ? 25 : 13;
            const int   st = (l == 0) ? 0 : (l == 1) ? 15200 : (l == 2) ? 19000 : 19950;

            const f16x2 ov = *(const f16x2*)&oa[row + head * 32 + lp * 2];
            const float2 rxy = *(const float2*)&ref[(size_t)tok * 8 + l * 2];
            const float x = rxy.x * fW + (float)ov.x - 0.5f;
            const float y = rxy.y * fH + (float)ov.y - 0.5f;
            const float xf = floorf(x), yf = floorf(y);
            const float fx = x - xf, fy = y - yf;
            const int x0 = (int)xf, y0 = (int)yf;

            const bool vx0 = (x0 >= 0) && (x0 < W);
            const bool vx1 = (x0 >= -1) && (x0 < W - 1);
            const bool vy0 = (y0 >= 0) && (y0 < H);
            const bool vy1 = (y0 >= -1) && (y0 < H - 1);
            const int x0c = min(max(x0, 0), W - 1), x1c = min(max(x0 + 1, 0), W - 1);
            const int y0c = min(max(y0, 0), H - 1), y1c = min(max(y0 + 1, 0), H - 1);

            const int n = (tok >= LQ) ? 1 : 0;
            // slab-relative byte offset: [M][32] f16 -> 64B per entry
            const unsigned int b00 = (unsigned int)(n * LQ + st + y0c * W + x0c) << 6;
            const unsigned int dx6 = (unsigned int)(x1c - x0c) << 6;          // 0 or 64
            const unsigned int dy6 = (unsigned int)((y1c - y0c) * W) << 6;    // <= 9728
            s_g[tl][lp] = make_uint2(b00, dx6 | (dy6 << 16));

            const f16 w00 = (f16)((vx0 && vy0) ? (1.f - fx) * (1.f - fy) * aw : 0.f);
            const f16 w01 = (f16)((vx1 && vy0) ? fx * (1.f - fy) * aw : 0.f);
            const f16 w10 = (f16)((vx0 && vy1) ? (1.f - fx) * fy * aw : 0.f);
            const f16 w11 = (f16)((vx1 && vy1) ? fx * fy * aw : 0.f);
            f16x4 wv = { w00, w01, w10, w11 };
            s_w[tl][lp] = wv;
        }
    }
    __syncthreads();

    const int tl = t >> 2, l4 = t & 3;
    const int tok = tok0 + tl;
    if (tok >= MTOT) return;
    const unsigned int lb = (unsigned int)l4 * 16u;
    const char* vbase = (const char*)valueT + (size_t)head * (MTOT * 64ull);

    f16x2 a0 = {}, a1 = {}, a2 = {}, a3 = {};
#pragma unroll 4
    for (int p = 0; p < 16; ++p) {
        const uint2 g  = s_g[tl][p];
        const f16x4 wv = s_w[tl][p];
        const unsigned int a00 = g.x + lb;
        const unsigned int dx6 = g.y & 0xFFFFu;
        const unsigned int dy6 = g.y >> 16;
        const f16x8 v00 = *(const f16x8*)(vbase + a00);
        const f16x8 v01 = *(const f16x8*)(vbase + (a00 + dx6));
        const f16x8 v10 = *(const f16x8*)(vbase + (a00 + dy6));
        const f16x8 v11 = *(const f16x8*)(vbase + (a00 + dy6 + dx6));
        const f16x2 w0 = { wv[0], wv[0] }, w1 = { wv[1], wv[1] };
        const f16x2 w2 = { wv[2], wv[2] }, w3 = { wv[3], wv[3] };
        const f16x2* p0 = (const f16x2*)&v00;
        const f16x2* p1 = (const f16x2*)&v01;
        const f16x2* p2 = (const f16x2*)&v10;
        const f16x2* p3 = (const f16x2*)&v11;
        a0 = a0 + p0[0] * w0; a1 = a1 + p0[1] * w0;
        a2 = a2 + p0[2] * w0; a3 = a3 + p0[3] * w0;
        a0 = a0 + p1[0] * w1; a1 = a1 + p1[1] * w1;
        a2 = a2 + p1[2] * w1; a3 = a3 + p1[3] * w1;
        a0 = a0 + p2[0] * w2; a1 = a1 + p2[1] * w2;
        a2 = a2 + p2[2] * w2; a3 = a3 + p2[3] * w2;
        a0 = a0 + p3[0] * w3; a1 = a1 + p3[1] * w3;
        a2 = a2 + p3[2] * w3; a3 = a3 + p3[3] * w3;
    }
    f16x8 o = { a0.x, a0.y, a1.x, a1.y, a2.x, a2.y, a3.x, a3.y };
    *(f16x8*)&samp[(size_t)tok * 256 + head * 32 + l4 * 8] = o;
}

// ---------------- LN (f16 inputs): y = LN(xa + xb)*g + b ----------------
// OUTF16=1 -> write f16, else f32
template<int OUTF16>
__global__ __launch_bounds__(256) void k_lnh(
    const f16* __restrict__ xa, const f16* __restrict__ xb,
    const float* __restrict__ g, const float* __restrict__ be,
    void* __restrict__ y, int M)
{
    const int row = blockIdx.x * 4 + (threadIdx.x >> 6);
    const int lane = threadIdx.x & 63;
    if (row >= M) return;
    const size_t o = (size_t)row * 256 + lane * 4;
    f16x4 a = *(const f16x4*)(xa + o);
    f16x4 b = *(const f16x4*)(xb + o);
    float x0 = (float)a.x + (float)b.x, x1 = (float)a.y + (float)b.y;
    float x2 = (float)a.z + (float)b.z, x3 = (float)a.w + (float)b.w;
    float s  = x0 + x1 + x2 + x3;
    float ss = x0*x0 + x1*x1 + x2*x2 + x3*x3;
#pragma unroll
    for (int m = 1; m < 64; m <<= 1) { s += __shfl_xor(s, m); ss += __shfl_xor(ss, m); }
    const float mean = s * (1.f / 256.f);
    const float var  = ss * (1.f / 256.f) - mean * mean;
    const float rstd = rsqrtf(var + 1e-5f);
    float4 gv = *(const float4*)(g + lane * 4);
    float4 bv = *(const float4*)(be + lane * 4);
    const float y0 = (x0 - mean) * rstd * gv.x + bv.x;
    const float y1 = (x1 - mean) * rstd * gv.y + bv.y;
    const float y2 = (x2 - mean) * rstd * gv.z + bv.z;
    const float y3 = (x3 - mean) * rstd * gv.w + bv.w;
    if (OUTF16) {
        f16x4 hv = { (f16)y0, (f16)y1, (f16)y2, (f16)y3 };
        *(f16x4*)((f16*)y + o) = hv;
    } else {
        float4 yo = { y0, y1, y2, y3 };
        *(float4*)((float*)y + o) = yo;
    }
}

// ---------------- launch ----------------
extern "C" void kernel_launch(void* const* d_in, const int* in_sizes, int n_in,
                              void* d_out, int out_size, void* d_ws, size_t ws_size,
                              hipStream_t stream) {
    const float* src   = (const float*)d_in[0];
    const float* pos   = (const float*)d_in[1];
    const float* ref   = (const float*)d_in[2];
    const float* w_value = (const float*)d_in[5];
    const float* b_value = (const float*)d_in[6];
    const float* w_off   = (const float*)d_in[7];
    const float* b_off   = (const float*)d_in[8];
    const float* w_attn  = (const float*)d_in[9];
    const float* b_attn  = (const float*)d_in[10];
    const float* w_out   = (const float*)d_in[11];
    const float* b_out   = (const float*)d_in[12];
    const float* g1    = (const float*)d_in[13];
    const float* beta1 = (const float*)d_in[14];
    const float* w1    = (const float*)d_in[15];
    const float* b1    = (const float*)d_in[16];
    const float* w2    = (const float*)d_in[17];
    const float* b2    = (const float*)d_in[18];
    const float* g2    = (const float*)d_in[19];
    const float* beta2 = (const float*)d_in[20];

    char* ws = (char*)d_ws;
    f16*   wT      = (f16*)(ws + 0);
    f16*   oa      = (f16*)(ws + OFF_B4);     // fused off|attn f16 [M,384]
    f16*   y2h     = (f16*)(ws + OFF_B4);     // later: FFN2 out f16 [M,256] (oa dead)
    f16*   srch    = (f16*)(ws + OFF_B1);     // src f16 (residual for LN1)
    f16*   qh      = (f16*)(ws + OFF_B2);     // query f16
    f16*   x1h     = (f16*)(ws + OFF_B2);     // later: LN1 out f16 (qh dead)
    f16*   valueT  = (f16*)(ws + OFF_B3);     // value f16 head-blocked [8][M][32]
    f16*   hh      = (f16*)(ws + OFF_B3);     // later: FFN hidden f16 [M,1024] (B3..B7)
    float* biasoa  = (float*)(ws + OFF_B5);   // concat bias f32 [384]
    f16*   src2h   = (f16*)(ws + OFF_B6);     // attn output f16 [M,256]
    f16*   samph   = (f16*)(ws + OFF_B7);     // sampled out f16 [M,256]
    float* outp    = (float*)d_out;

    const int M = MTOT;
    const int MB = (M + 127) / 128;
    auto grid8 = [&](int nb) { return ((MB * nb) + 7) & ~7; };   // pad to %8 for swizzle

    // fused weight-convert + bias-concat + prep (one dispatch)
    k_wconv_prep<<<(FUSED_TOTAL + 255) / 256, 256, 0, stream>>>(
        w_value, w_off, w_attn, w_out, w1, w2, b_off, b_attn, wT, biasoa,
        src, pos, srch, qh);

    // value = src @ w_value + b_value -> head-blocked f16
    k_gemm128<false, 2><<<grid8(2), 256, 0, stream>>>(srch, wT + WT_V, b_value, valueT, M, 256, 256);
    // fused off|attn logits -> f16 [M,384]
    k_gemm128<false, 1><<<grid8(3), 256, 0, stream>>>(qh, wT + WT_OFF, biasoa, oa, M, 384, 256);
    // softmax + bilinear sampling: head-split, head = blockIdx.x & 7 -> XCD
    {
        const int nchunk = (MTOT + 63) / 64;   // 632
        k_sample<<<dim3(nchunk * 8), 256, 0, stream>>>(oa, valueT, ref, samph);
    }
    // out projection -> src2 f16
    k_gemm128<false, 1><<<grid8(2), 256, 0, stream>>>(samph, wT + WT_OUT, b_out, src2h, M, 256, 256);
    // LN1: x1h = LN(srch + src2h) f16
    k_lnh<1><<<(M + 3) / 4, 256, 0, stream>>>(srch, src2h, g1, beta1, x1h, M);
    // FFN1: h = relu(x1 @ w1 + b1) f16
    k_gemm128<true, 1><<<grid8(8), 256, 0, stream>>>(x1h, wT + WT_W1, b1, hh, M, 1024, 256);
    // FFN2: y2 = h @ w2 + b2 -> f16
    k_gemm128<false, 1><<<grid8(2), 256, 0, stream>>>(hh, wT + WT_W2, b2, y2h, M, 256, 1024);
    // LN2 -> d_out f32
    k_lnh<0><<<(M + 3) / 4, 256, 0, stream>>>(x1h, y2h, g2, beta2, outp, M);

    (void)in_sizes; (void)n_in; (void)out_size; (void)ws_size;
}

// Round 14
// 211.277 us; speedup vs baseline: 1.6103x; 1.0434x over previous
//
#include <hip/hip_runtime.h>

// ---------------- problem constants ----------------
#define LQ   20197
#define MTOT 40394           // 2 * 20197

typedef _Float16 f16;
typedef _Float16 f16x8 __attribute__((ext_vector_type(8)));
typedef _Float16 f16x4 __attribute__((ext_vector_type(4)));
typedef _Float16 f16x2 __attribute__((ext_vector_type(2)));
typedef float    f32x4 __attribute__((ext_vector_type(4)));

// ---------------- workspace layout (bytes) ----------------
#define OFF_B4 1507328ull      // oa f16 [M,384] -> later y2h f16 [M,256]
#define OFF_B1 42870784ull     // src f16 (residual for LN1)
#define OFF_B2 63552512ull     // query f16 -> later x1h f16
#define OFF_B3 84234240ull     // valueT f16 [8][M][32]; later FFN hidden hh (B3..B7)
#define OFF_B5 104915968ull    // 128B pad (valueT pair-load overrun) + bias_oa f32 [384]
#define OFF_B6 125597696ull    // src2h f16 [M,256] (consumed before FFN1)
#define OFF_B7 166961152ull    // samph f16 [M,256] (consumed by out-proj GEMM)

// wT element offsets (f16 elements)
#define WT_V    0
#define WT_OFF  65536          // off rows [256][256] then attn rows [128][256] contiguous
#define WT_ATTN 131072
#define WT_OUT  163840
#define WT_W1   229376
#define WT_W2   491520
#define WT_TOTAL 753664
#define WCONV_TOTAL (WT_TOTAL + 384)
#define PREP_TOTAL (MTOT * 64)          // float4 groups
#define FUSED_TOTAL (WCONV_TOTAL + PREP_TOTAL)

// ---------------- async global->LDS, 16B per lane ----------------
__device__ __forceinline__ void gload_lds16(const f16* g, f16* l) {
    __builtin_amdgcn_global_load_lds(
        (const __attribute__((address_space(1))) unsigned int*)g,
        (__attribute__((address_space(3))) unsigned int*)l,
        16, 0, 0);
}

// ---------------- fused: weight transpose+convert + bias concat + prep ----------------
__global__ __launch_bounds__(256) void k_wconv_prep(
    const float* __restrict__ wv, const float* __restrict__ woff,
    const float* __restrict__ wattn, const float* __restrict__ wout,
    const float* __restrict__ w1, const float* __restrict__ w2,
    const float* __restrict__ boff, const float* __restrict__ battn,
    f16* __restrict__ dst, float* __restrict__ biasoa,
    const float* __restrict__ srcf, const float* __restrict__ posf,
    f16* __restrict__ srch, f16* __restrict__ qh)
{
    int gid = blockIdx.x * 256 + threadIdx.x;
    if (gid >= FUSED_TOTAL) return;
    if (gid >= WCONV_TOTAL) {
        const int i = gid - WCONV_TOTAL;
        float4 s = ((const float4*)srcf)[i];
        float4 p = ((const float4*)posf)[i];
        f16x4 hs = { (f16)s.x, (f16)s.y, (f16)s.z, (f16)s.w };
        f16x4 hq = { (f16)(s.x + p.x), (f16)(s.y + p.y), (f16)(s.z + p.z), (f16)(s.w + p.w) };
        ((f16x4*)srch)[i] = hs;
        ((f16x4*)qh)[i]   = hq;
        return;
    }
    if (gid >= WT_TOTAL) {
        int i = gid - WT_TOTAL;
        biasoa[i] = (i < 256) ? boff[i] : battn[i - 256];
        return;
    }
    const float* src; int Kd, Nd, base;
    if      (gid < 65536)  { src = wv;    Kd = 256;  Nd = 256;  base = 0; }
    else if (gid < 131072) { src = woff;  Kd = 256;  Nd = 256;  base = 65536; }
    else if (gid < 163840) { src = wattn; Kd = 256;  Nd = 128;  base = 131072; }
    else if (gid < 229376) { src = wout;  Kd = 256;  Nd = 256;  base = 163840; }
    else if (gid < 491520) { src = w1;    Kd = 256;  Nd = 1024; base = 229376; }
    else                   { src = w2;    Kd = 1024; Nd = 256;  base = 491520; }
    int loc = gid - base;
    int n = loc % Nd, k = loc / Nd;
    dst[base + n * Kd + k] = (f16)src[k * Nd + n];
}

// ---------------- GEMM 128x128 tile, BK=32, dbuf global_load_lds, XCD swizzle ----------------
// C[M,N] = A[M,K](f16) * Bt[N,K](f16)^T + bias ; N % 128 == 0 assumed.
// OUTM: 1 = f16 row-major [M][N], 2 = f16 head-blocked [N/32][M][32]
template<bool RELU, int OUTM>
__global__ __launch_bounds__(256) void k_gemm128(
    const f16* __restrict__ A, const f16* __restrict__ Bt,
    const float* __restrict__ bias, void* __restrict__ Cout,
    int M, int N, int K)
{
    __shared__ __align__(16) char pool[34816];   // staging 32KB  |  C-tile 128*136*2B
    f16* const sm = (f16*)pool;

    const int NBn = N >> 7;
    const int MBn = (M + 127) >> 7;
    const int tiles = MBn * NBn;
    const int q = gridDim.x >> 3;                 // grid padded to %8
    const int bid = blockIdx.x;
    const int swz = (bid & 7) * q + (bid >> 3);   // bijective XCD swizzle
    if (swz >= tiles) return;
    const int m0 = (swz / NBn) << 7;
    const int n0 = (swz % NBn) << 7;

    const int t = threadIdx.x, wid = t >> 6, lane = t & 63;

    const int c0 = wid, c1 = wid + 4;
    const int sr = lane >> 2, sk = (lane & 3) * 8;
    const int ra0 = min(m0 + c0 * 16 + sr, M - 1);
    const int ra1 = min(m0 + c1 * 16 + sr, M - 1);
    const f16* pa0 = A + (size_t)ra0 * K + sk;
    const f16* pa1 = A + (size_t)ra1 * K + sk;
    const f16* pb0 = Bt + (size_t)(n0 + c0 * 16 + sr) * K + sk;
    const f16* pb1 = Bt + (size_t)(n0 + c1 * 16 + sr) * K + sk;
    const int lo0 = c0 * 512, lo1 = c1 * 512;

    const int wr = wid >> 1, wc = wid & 1;
    const int fr = lane & 15, kb = (lane >> 4) * 8;

    f32x4 acc[4][4] = {};
    const int NT = K >> 5;

    gload_lds16(pa0, sm + lo0);
    gload_lds16(pa1, sm + lo1);
    gload_lds16(pb0, sm + 4096 + lo0);
    gload_lds16(pb1, sm + 4096 + lo1);
    __syncthreads();

    for (int tt = 0; tt < NT; ++tt) {
        const int cur = (tt & 1) << 13, nxt = cur ^ 8192;
        if (tt + 1 < NT) {
            const int k0 = (tt + 1) << 5;
            gload_lds16(pa0 + k0, sm + nxt + lo0);
            gload_lds16(pa1 + k0, sm + nxt + lo1);
            gload_lds16(pb0 + k0, sm + nxt + 4096 + lo0);
            gload_lds16(pb1 + k0, sm + nxt + 4096 + lo1);
        }
        f16x8 af[4], bf[4];
#pragma unroll
        for (int i = 0; i < 4; ++i)
            af[i] = *(const f16x8*)&sm[cur + (wr * 64 + i * 16 + fr) * 32 + kb];
#pragma unroll
        for (int i = 0; i < 4; ++i)
            bf[i] = *(const f16x8*)&sm[cur + 4096 + (wc * 64 + i * 16 + fr) * 32 + kb];
#pragma unroll
        for (int mi = 0; mi < 4; ++mi)
#pragma unroll
            for (int ni = 0; ni < 4; ++ni)
                acc[mi][ni] = __builtin_amdgcn_mfma_f32_16x16x32_f16(af[mi], bf[ni], acc[mi][ni], 0, 0, 0);
        __syncthreads();
    }

    // ---- epilogue: acc -> LDS (stride 136) -> coalesced global ----
    const int r4 = (lane >> 4) * 4;
#pragma unroll
    for (int ni = 0; ni < 4; ++ni) {
        const int lcol = wc * 64 + ni * 16 + fr;
        const float bv = bias[n0 + lcol];
#pragma unroll
        for (int mi = 0; mi < 4; ++mi) {
#pragma unroll
            for (int j = 0; j < 4; ++j) {
                float v = acc[mi][ni][j] + bv;
                if (RELU) v = fmaxf(v, 0.f);
                sm[(wr * 64 + mi * 16 + r4 + j) * 136 + lcol] = (f16)v;
            }
        }
    }
    __syncthreads();

    if (OUTM == 1) {
        const int rr = t >> 4, cc = (t & 15) * 8;
#pragma unroll
        for (int pass = 0; pass < 8; ++pass) {
            const int r = pass * 16 + rr;
            const int row = m0 + r;
            if (row < M) {
                f16x8 v = *(const f16x8*)&sm[r * 136 + cc];
                *(f16x8*)&((f16*)Cout)[(size_t)row * N + n0 + cc] = v;
            }
        }
    } else {
        const int cbl = t >> 6, rr = (t & 63) >> 2, cc = (t & 3) * 8;
        const size_t cb = (size_t)((n0 >> 5) + cbl);
#pragma unroll
        for (int pass = 0; pass < 8; ++pass) {
            const int r = pass * 16 + rr;
            const int row = m0 + r;
            if (row < M) {
                f16x8 v = *(const f16x8*)&sm[r * 136 + cbl * 32 + cc];
                *(f16x8*)&((f16*)Cout)[(cb * M + row) * 32 + cc] = v;
            }
        }
    }
}

// ---------------- fused softmax + deformable bilinear sampling ----------------
// HEAD-SPLIT (head = blockIdx.x & 7 -> XCD; slab 2.59MB < 4MB L2) +
// CORNER-PAIR loads: x-corners are adjacent 64B entries, so each corner quad is
// two contiguous 128B spans (y0-row, y1-row). 8 lanes per (tok,head) = 2 x-corners
// x 4 dim-quarters issue each span as ONE fully-coalesced instruction; final
// shfl_xor(4) pair-reduce. Pair base pixel bx = clamp(x0,-1,W-1): masked halves
// read finite garbage x 0-weight (valueT padded 128B; bx=-1 reads valid ws).
__global__ __launch_bounds__(256) void k_sample(
    const f16* __restrict__ oa, const f16* __restrict__ valueT,
    const float* __restrict__ ref, f16* __restrict__ samp)
{
    __shared__ int2  s_g[32][17];   // (b00 signed bytes, dy6); pad 17 for banks
    __shared__ f16x4 s_w[32][17];   // (w00,w01,w10,w11) premultiplied by attn
    const int head = blockIdx.x & 7;
    const int tok0 = (blockIdx.x >> 3) * 32;
    const int t = threadIdx.x;

#pragma unroll
    for (int it = 0; it < 2; ++it) {
        const int tl = it * 16 + (t >> 4);
        const int lp = t & 15, l = lp >> 2;
        const int tok = tok0 + tl;
        if (tok < MTOT) {
            const size_t row = (size_t)tok * 384;
            float logit = (float)oa[row + 256 + head * 16 + lp];
            float mx = logit;
#pragma unroll
            for (int m = 1; m < 16; m <<= 1) mx = fmaxf(mx, __shfl_xor(mx, m));
            float e = __expf(logit - mx);
            float sum = e;
#pragma unroll
            for (int m = 1; m < 16; m <<= 1) sum += __shfl_xor(sum, m);
            const float aw = e / sum;

            const float fW = (l == 0) ? 152.f : (l == 1) ? 76.f : (l == 2) ? 38.f : 19.f;
            const float fH = (l == 0) ? 100.f : (l == 1) ? 50.f : (l == 2) ? 25.f : 13.f;
            const int   W  = (l == 0) ? 152 : (l == 1) ? 76 : (l == 2) ? 38 : 19;
            const int   H  = (l == 0) ? 100 : (l == 1) ? 50 : (l == 2) ? 25 : 13;
            const int   st = (l == 0) ? 0 : (l == 1) ? 15200 : (l == 2) ? 19000 : 19950;

            const f16x2 ov = *(const f16x2*)&oa[row + head * 32 + lp * 2];
            const float2 rxy = *(const float2*)&ref[(size_t)tok * 8 + l * 2];
            const float x = rxy.x * fW + (float)ov.x - 0.5f;
            const float y = rxy.y * fH + (float)ov.y - 0.5f;
            const float xf = floorf(x), yf = floorf(y);
            const float fx = x - xf, fy = y - yf;
            const int x0 = (int)xf, y0 = (int)yf;

            const bool vx0 = (x0 >= 0) && (x0 < W);
            const bool vx1 = (x0 >= -1) && (x0 < W - 1);
            const bool vy0 = (y0 >= 0) && (y0 < H);
            const bool vy1 = (y0 >= -1) && (y0 < H - 1);
            const int y0c = min(max(y0, 0), H - 1), y1c = min(max(y0 + 1, 0), H - 1);
            const int bx  = min(max(x0, -1), W - 1);   // pair base: bx=x0c when w00!=0, bx+1=x1c when w01!=0

            const int n = (tok >= LQ) ? 1 : 0;
            const int b00 = (n * LQ + st + y0c * W + bx) << 6;       // signed, can be -64
            const int dy6 = ((y1c - y0c) * W) << 6;                  // 0 or W*64
            s_g[tl][lp] = make_int2(b00, dy6);

            const f16 w00 = (f16)((vx0 && vy0) ? (1.f - fx) * (1.f - fy) * aw : 0.f);
            const f16 w01 = (f16)((vx1 && vy0) ? fx * (1.f - fy) * aw : 0.f);
            const f16 w10 = (f16)((vx0 && vy1) ? (1.f - fx) * fy * aw : 0.f);
            const f16 w11 = (f16)((vx1 && vy1) ? fx * fy * aw : 0.f);
            f16x4 wv = { w00, w01, w10, w11 };
            s_w[tl][lp] = wv;
        }
    }
    __syncthreads();

    const int tl = t >> 3;            // 32 tokens
    const int g3 = t & 7;             // 8 lanes per (tok,head): 128B span
    const int xc = g3 >> 2;           // x-corner half (0 -> w00/w10, 1 -> w01/w11)
    const int l4 = g3 & 3;            // dim quarter within the 64B entry
    const int tok = tok0 + tl;
    if (tok >= MTOT) return;
    const int lb = g3 * 16;           // byte offset within the 128B pair span
    const char* vbase = (const char*)valueT + (size_t)head * (MTOT * 64ull);

    f16x2 a0 = {}, a1 = {}, a2 = {}, a3 = {};
#pragma unroll 4
    for (int p = 0; p < 16; ++p) {
        const int2  g  = s_g[tl][p];
        const f16x4 wv = s_w[tl][p];
        const char* base = vbase + (g.x + lb);
        const f16x8 vA = *(const f16x8*)(base);          // y0-row span (coalesced 128B/8 lanes)
        const f16x8 vB = *(const f16x8*)(base + g.y);    // y1-row span
        const f16 wa = xc ? wv[1] : wv[0];
        const f16 wb = xc ? wv[3] : wv[2];
        const f16x2 wA = { wa, wa }, wB = { wb, wb };
        const f16x2* pA = (const f16x2*)&vA;
        const f16x2* pB = (const f16x2*)&vB;
        a0 = a0 + pA[0] * wA; a1 = a1 + pA[1] * wA;
        a2 = a2 + pA[2] * wA; a3 = a3 + pA[3] * wA;
        a0 = a0 + pB[0] * wB; a1 = a1 + pB[1] * wB;
        a2 = a2 + pB[2] * wB; a3 = a3 + pB[3] * wB;
    }

    // pair-reduce across the two x-corner halves (partner lane t^4, same wave)
    union { f16x2 h; int i; } u0, u1, u2, u3;
    u0.h = a0; u1.h = a1; u2.h = a2; u3.h = a3;
    union { int i; f16x2 h; } r0, r1, r2, r3;
    r0.i = __shfl_xor(u0.i, 4); r1.i = __shfl_xor(u1.i, 4);
    r2.i = __shfl_xor(u2.i, 4); r3.i = __shfl_xor(u3.i, 4);
    a0 = a0 + r0.h; a1 = a1 + r1.h; a2 = a2 + r2.h; a3 = a3 + r3.h;

    // each half writes 4 dims (8B, coalesced)
    f16x4 o = xc ? (f16x4){ a2.x, a2.y, a3.x, a3.y }
                 : (f16x4){ a0.x, a0.y, a1.x, a1.y };
    *(f16x4*)&samp[(size_t)tok * 256 + head * 32 + l4 * 8 + xc * 4] = o;
}

// ---------------- LN (f16 inputs): y = LN(xa + xb)*g + b ----------------
// OUTF16=1 -> write f16, else f32
template<int OUTF16>
__global__ __launch_bounds__(256) void k_lnh(
    const f16* __restrict__ xa, const f16* __restrict__ xb,
    const float* __restrict__ g, const float* __restrict__ be,
    void* __restrict__ y, int M)
{
    const int row = blockIdx.x * 4 + (threadIdx.x >> 6);
    const int lane = threadIdx.x & 63;
    if (row >= M) return;
    const size_t o = (size_t)row * 256 + lane * 4;
    f16x4 a = *(const f16x4*)(xa + o);
    f16x4 b = *(const f16x4*)(xb + o);
    float x0 = (float)a.x + (float)b.x, x1 = (float)a.y + (float)b.y;
    float x2 = (float)a.z + (float)b.z, x3 = (float)a.w + (float)b.w;
    float s  = x0 + x1 + x2 + x3;
    float ss = x0*x0 + x1*x1 + x2*x2 + x3*x3;
#pragma unroll
    for (int m = 1; m < 64; m <<= 1) { s += __shfl_xor(s, m); ss += __shfl_xor(ss, m); }
    const float mean = s * (1.f / 256.f);
    const float var  = ss * (1.f / 256.f) - mean * mean;
    const float rstd = rsqrtf(var + 1e-5f);
    float4 gv = *(const float4*)(g + lane * 4);
    float4 bv = *(const float4*)(be + lane * 4);
    const float y0 = (x0 - mean) * rstd * gv.x + bv.x;
    const float y1 = (x1 - mean) * rstd * gv.y + bv.y;
    const float y2 = (x2 - mean) * rstd * gv.z + bv.z;
    const float y3 = (x3 - mean) * rstd * gv.w + bv.w;
    if (OUTF16) {
        f16x4 hv = { (f16)y0, (f16)y1, (f16)y2, (f16)y3 };
        *(f16x4*)((f16*)y + o) = hv;
    } else {
        float4 yo = { y0, y1, y2, y3 };
        *(float4*)((float*)y + o) = yo;
    }
}

// ---------------- launch ----------------
extern "C" void kernel_launch(void* const* d_in, const int* in_sizes, int n_in,
                              void* d_out, int out_size, void* d_ws, size_t ws_size,
                              hipStream_t stream) {
    const float* src   = (const float*)d_in[0];
    const float* pos   = (const float*)d_in[1];
    const float* ref   = (const float*)d_in[2];
    const float* w_value = (const float*)d_in[5];
    const float* b_value = (const float*)d_in[6];
    const float* w_off   = (const float*)d_in[7];
    const float* b_off   = (const float*)d_in[8];
    const float* w_attn  = (const float*)d_in[9];
    const float* b_attn  = (const float*)d_in[10];
    const float* w_out   = (const float*)d_in[11];
    const float* b_out   = (const float*)d_in[12];
    const float* g1    = (const float*)d_in[13];
    const float* beta1 = (const float*)d_in[14];
    const float* w1    = (const float*)d_in[15];
    const float* b1    = (const float*)d_in[16];
    const float* w2    = (const float*)d_in[17];
    const float* b2    = (const float*)d_in[18];
    const float* g2    = (const float*)d_in[19];
    const float* beta2 = (const float*)d_in[20];

    char* ws = (char*)d_ws;
    f16*   wT      = (f16*)(ws + 0);
    f16*   oa      = (f16*)(ws + OFF_B4);     // fused off|attn f16 [M,384]
    f16*   y2h     = (f16*)(ws + OFF_B4);     // later: FFN2 out f16 [M,256] (oa dead)
    f16*   srch    = (f16*)(ws + OFF_B1);     // src f16 (residual for LN1)
    f16*   qh      = (f16*)(ws + OFF_B2);     // query f16
    f16*   x1h     = (f16*)(ws + OFF_B2);     // later: LN1 out f16 (qh dead)
    f16*   valueT  = (f16*)(ws + OFF_B3);     // value f16 head-blocked [8][M][32]
    f16*   hh      = (f16*)(ws + OFF_B3);     // later: FFN hidden f16 [M,1024] (B3..B7)
    float* biasoa  = (float*)(ws + OFF_B5 + 128);  // concat bias f32 [384], after 128B pad
    f16*   src2h   = (f16*)(ws + OFF_B6);     // attn output f16 [M,256]
    f16*   samph   = (f16*)(ws + OFF_B7);     // sampled out f16 [M,256]
    float* outp    = (float*)d_out;

    const int M = MTOT;
    const int MB = (M + 127) / 128;
    auto grid8 = [&](int nb) { return ((MB * nb) + 7) & ~7; };   // pad to %8 for swizzle

    // fused weight-convert + bias-concat + prep (one dispatch)
    k_wconv_prep<<<(FUSED_TOTAL + 255) / 256, 256, 0, stream>>>(
        w_value, w_off, w_attn, w_out, w1, w2, b_off, b_attn, wT, biasoa,
        src, pos, srch, qh);

    // value = src @ w_value + b_value -> head-blocked f16
    k_gemm128<false, 2><<<grid8(2), 256, 0, stream>>>(srch, wT + WT_V, b_value, valueT, M, 256, 256);
    // fused off|attn logits -> f16 [M,384]
    k_gemm128<false, 1><<<grid8(3), 256, 0, stream>>>(qh, wT + WT_OFF, biasoa, oa, M, 384, 256);
    // softmax + bilinear sampling: head-split + corner-pair loads (32 tok/block)
    {
        const int nchunk = (MTOT + 31) / 32;   // 1263
        k_sample<<<dim3(nchunk * 8), 256, 0, stream>>>(oa, valueT, ref, samph);
    }
    // out projection -> src2 f16
    k_gemm128<false, 1><<<grid8(2), 256, 0, stream>>>(samph, wT + WT_OUT, b_out, src2h, M, 256, 256);
    // LN1: x1h = LN(srch + src2h) f16
    k_lnh<1><<<(M + 3) / 4, 256, 0, stream>>>(srch, src2h, g1, beta1, x1h, M);
    // FFN1: h = relu(x1 @ w1 + b1) f16
    k_gemm128<true, 1><<<grid8(8), 256, 0, stream>>>(x1h, wT + WT_W1, b1, hh, M, 1024, 256);
    // FFN2: y2 = h @ w2 + b2 -> f16
    k_gemm128<false, 1><<<grid8(2), 256, 0, stream>>>(hh, wT + WT_W2, b2, y2h, M, 256, 1024);
    // LN2 -> d_out f32
    k_lnh<0><<<(M + 3) / 4, 256, 0, stream>>>(x1h, y2h, g2, beta2, outp, M);

    (void)in_sizes; (void)n_in; (void)out_size; (void)ws_size;
}